// Round 6
// baseline (757.617 us; speedup 1.0000x reference)
//
#include <hip/hip_runtime.h>
#include <math.h>

#define NEG_SLOPE 0.2f

// ---------------- node transform for conv1: h1 = x@W1, a_src1, a_dst1 ----------------
__global__ void k_node1(const float* __restrict__ x, const float* __restrict__ W1,
                        const float* __restrict__ as1, const float* __restrict__ ad1,
                        float* __restrict__ h1, float* __restrict__ a_src1,
                        float* __restrict__ a_dst1, int N) {
    int n = blockIdx.x * blockDim.x + threadIdx.x;
    if (n >= N) return;
    float xv[8];
#pragma unroll
    for (int k = 0; k < 8; k++) xv[k] = x[n * 8 + k];
    float h[32];
#pragma unroll
    for (int j = 0; j < 32; j++) {
        float acc = 0.f;
#pragma unroll
        for (int k = 0; k < 8; k++) acc += xv[k] * W1[k * 32 + j];
        h[j] = acc;
        h1[n * 32 + j] = acc;
    }
#pragma unroll
    for (int hh = 0; hh < 2; hh++) {
        float s = 0.f, d = 0.f;
#pragma unroll
        for (int c = 0; c < 16; c++) {
            s += h[hh * 16 + c] * as1[hh * 16 + c];
            d += h[hh * 16 + c] * ad1[hh * 16 + c];
        }
        a_src1[n * 2 + hh] = s;
        a_dst1[n * 2 + hh] = d;
    }
}

// ---------------- CSR build ----------------
__global__ void k_deg_init(int* __restrict__ deg, int* __restrict__ rowptr, int N, int E) {
    int n = blockIdx.x * blockDim.x + threadIdx.x;
    if (n < N) deg[n] = 1;  // self-loop
    if (n == 0) rowptr[N] = E + N;
}

__global__ void k_deg_count(const int* __restrict__ ei, int* __restrict__ deg, int E) {
    int e = blockIdx.x * blockDim.x + threadIdx.x;
    if (e < E) atomicAdd(&deg[ei[E + e]], 1);  // dst
}

// 1024-thread single-block hierarchical scan (R2 verbatim)
__global__ void k_scan(const int* __restrict__ deg, int* __restrict__ rowptr,
                       int* __restrict__ cursor, int N) {
    __shared__ int wsum[16];
    __shared__ int wpre[16];
    int tid = threadIdx.x;
    int lane = tid & 63, wid = tid >> 6;
    int chunk = (N + 1023) >> 10;
    int beg = tid * chunk;
    int end = beg + chunk; if (end > N) end = N;
    int s = 0;
    for (int i = beg; i < end; i++) s += deg[i];
    int incl = s;
#pragma unroll
    for (int off = 1; off < 64; off <<= 1) {
        int v = __shfl_up(incl, off);
        if (lane >= off) incl += v;
    }
    if (lane == 63) wsum[wid] = incl;
    __syncthreads();
    if (tid == 0) {
        int r = 0;
        for (int i = 0; i < 16; i++) { wpre[i] = r; r += wsum[i]; }
    }
    __syncthreads();
    int run = wpre[wid] + incl - s;
    for (int i = beg; i < end; i++) {
        rowptr[i] = run;
        cursor[i] = run;
        run += deg[i];
    }
}

// scatter with original-edge-id tracking (eid = -1 for appended self-loops)
__global__ void k_scatter(const int* __restrict__ ei, int* __restrict__ cursor,
                          int* __restrict__ adj, int* __restrict__ eid, int E, int N) {
    int i = blockIdx.x * blockDim.x + threadIdx.x;
    if (i >= E + N) return;
    int s, d, id;
    if (i < E) { s = ei[i]; d = ei[E + i]; id = i; }
    else { s = i - E; d = i - E; id = -1; }
    int pos = atomicAdd(&cursor[d], 1);
    adj[pos] = s;
    eid[pos] = id;
}

// ---------------- conv1: 2 nodes/wave, two-pass exact softmax, per-lane head values ----------------
__global__ void k_conv1(const int* __restrict__ rowptr, const int* __restrict__ adj,
                        const float* __restrict__ a_src, const float* __restrict__ a_dst,
                        const float* __restrict__ h1, const float* __restrict__ b1,
                        float* __restrict__ out1, int N) {
    int lane = threadIdx.x & 63;
    int wave = (blockIdx.x * blockDim.x + threadIdx.x) >> 6;
    int sub = lane & 31;           // channel 0..31
    int slot = lane >> 5;
    int hh = sub >> 4;             // head of this lane's channel
    int n = wave * 2 + slot;
    if (n >= N) return;
    int beg = rowptr[n], end = rowptr[n + 1];
    float ad = a_dst[n * 2 + hh];
    // pass 1: exact max, 16 lanes per (node,head), strided over edges
    float m = -1e30f;
    for (int i = beg + (sub & 15); i < end; i += 16) {
        int s = adj[i];
        float t = a_src[s * 2 + hh] + ad;
        t = t > 0.f ? t : NEG_SLOPE * t;
        m = fmaxf(m, t);
    }
#pragma unroll
    for (int off = 8; off >= 1; off >>= 1) m = fmaxf(m, __shfl_xor(m, off));
    // pass 2: weighted aggregate; only the (head-independent) src index crosses lanes
    float denom = 0.f, acc = 0.f;
    for (int j0 = beg; j0 < end; j0 += 32) {
        int idx = j0 + sub;
        int av = (idx < end) ? adj[idx] : 0;
        int cnt = end - j0; if (cnt > 32) cnt = 32;
#pragma unroll 8
        for (int jj = 0; jj < cnt; jj++) {
            int s = __shfl(av, jj, 32);
            float t = a_src[s * 2 + hh] + ad;
            t = t > 0.f ? t : NEG_SLOPE * t;
            float wgt = __expf(t - m);
            acc += wgt * h1[s * 32 + sub];
            denom += wgt;
        }
    }
    out1[n * 32 + sub] = fmaxf(acc / denom + b1[sub], 0.f);
}

// ---------------- node transform for conv2 ----------------
__global__ void k_node2(const float* __restrict__ out1, const float* __restrict__ W2,
                        const float* __restrict__ as2, const float* __restrict__ ad2,
                        float* __restrict__ h2, float* __restrict__ a_src2,
                        float* __restrict__ a_dst2, int N) {
    int lane = threadIdx.x & 63;
    int n = (blockIdx.x * blockDim.x + threadIdx.x) >> 6;
    if (n >= N) return;
    float acc = 0.f;
#pragma unroll
    for (int k = 0; k < 32; k++) acc += out1[n * 32 + k] * W2[k * 64 + lane];
    h2[n * 64 + lane] = acc;
    float s = acc * as2[lane];
    float d = acc * ad2[lane];
#pragma unroll
    for (int off = 16; off >= 1; off >>= 1) {
        s += __shfl_xor(s, off);
        d += __shfl_xor(d, off);
    }
    if ((lane & 31) == 0) {
        a_src2[n * 2 + (lane >> 5)] = s;
        a_dst2[n * 2 + (lane >> 5)] = d;
    }
}

// ---------------- conv2: 1 node/wave, two-pass exact softmax ----------------
__global__ void k_conv2(const int* __restrict__ rowptr, const int* __restrict__ adj,
                        const float* __restrict__ a_src, const float* __restrict__ a_dst,
                        const float* __restrict__ h2, const float* __restrict__ b2,
                        float* __restrict__ hfin, int N) {
    int lane = threadIdx.x & 63;
    int n = (blockIdx.x * blockDim.x + threadIdx.x) >> 6;
    if (n >= N) return;
    int hh = lane >> 5;
    int beg = rowptr[n], end = rowptr[n + 1];
    float ad = a_dst[n * 2 + hh];
    // pass 1: exact max, 32 lanes per head, strided
    float m = -1e30f;
    for (int i = beg + (lane & 31); i < end; i += 32) {
        int s = adj[i];
        float t = a_src[s * 2 + hh] + ad;
        t = t > 0.f ? t : NEG_SLOPE * t;
        m = fmaxf(m, t);
    }
#pragma unroll
    for (int off = 16; off >= 1; off >>= 1) m = fmaxf(m, __shfl_xor(m, off));
    // pass 2
    float denom = 0.f, acc = 0.f;
    for (int j0 = beg; j0 < end; j0 += 64) {
        int idx = j0 + lane;
        int av = (idx < end) ? adj[idx] : 0;
        int cnt = end - j0; if (cnt > 64) cnt = 64;
#pragma unroll 8
        for (int jj = 0; jj < cnt; jj++) {
            int s = __shfl(av, jj);
            float t = a_src[s * 2 + hh] + ad;
            t = t > 0.f ? t : NEG_SLOPE * t;
            float wgt = __expf(t - m);
            acc += wgt * h2[s * 64 + lane];
            denom += wgt;
        }
    }
    hfin[n * 64 + lane] = fmaxf(acc / denom + b2[lane], 0.f);
}

// ---------------- per-node fc1: g = hfin @ fc1_w + 0.5*b1 ----------------
__global__ void k_fc1node(const float* __restrict__ hfin, const float* __restrict__ w1,
                          const float* __restrict__ b1, float* __restrict__ g, int N) {
    int lane = threadIdx.x & 63;
    int n = (blockIdx.x * blockDim.x + threadIdx.x) >> 6;
    if (n >= N) return;
    float hv = hfin[n * 64 + lane];
    float acc = 0.5f * b1[lane];
#pragma unroll
    for (int k = 0; k < 64; k++) acc += __shfl(hv, k) * w1[k * 64 + lane];
    g[n * 64 + lane] = acc;
}

// ---------------- edge head, CSR-grouped: wave per dst node, coalesced g[r] gathers ----------------
__global__ void k_head3(const int* __restrict__ rowptr, const int* __restrict__ adj,
                        const int* __restrict__ eid, const float* __restrict__ g,
                        const float* __restrict__ w2, const float* __restrict__ b2,
                        float* __restrict__ out, int N) {
    int lane = threadIdx.x & 63;
    int n = (blockIdx.x * blockDim.x + threadIdx.x) >> 6;
    if (n >= N) return;
    int beg = rowptr[n], end = rowptr[n + 1];
    float gd = g[(size_t)n * 64 + lane];
    float wl = w2[lane];
    float bb = b2[0];
    for (int j0 = beg; j0 < end; j0 += 64) {
        int idx = j0 + lane;
        int av = (idx < end) ? adj[idx] : 0;
        int evv = (idx < end) ? eid[idx] : -1;
        int cnt = end - j0; if (cnt > 64) cnt = 64;
#pragma unroll 4
        for (int jj = 0; jj < cnt; jj++) {
            int id = __shfl(evv, jj);
            if (id < 0) continue;        // appended self-loop: not an output edge
            int r = __shfl(av, jj);
            float v = g[(size_t)r * 64 + lane];
            float xx = fmaxf(gd + v, 0.f) * wl;
#pragma unroll
            for (int off = 32; off >= 1; off >>= 1) xx += __shfl_xor(xx, off);
            if (lane == 0) out[id] = xx + bb;
        }
    }
}

extern "C" void kernel_launch(void* const* d_in, const int* in_sizes, int n_in,
                              void* d_out, int out_size, void* d_ws, size_t ws_size,
                              hipStream_t stream) {
    const float* x   = (const float*)d_in[0];
    const int*   ei  = (const int*)d_in[1];
    const float* W1  = (const float*)d_in[2];
    const float* as1 = (const float*)d_in[3];
    const float* ad1 = (const float*)d_in[4];
    const float* b1  = (const float*)d_in[5];
    const float* W2  = (const float*)d_in[6];
    const float* as2 = (const float*)d_in[7];
    const float* ad2 = (const float*)d_in[8];
    const float* b2  = (const float*)d_in[9];
    const float* fw1 = (const float*)d_in[10];
    const float* fb1 = (const float*)d_in[11];
    const float* fw2 = (const float*)d_in[12];
    const float* fb2 = (const float*)d_in[13];
    float* out = (float*)d_out;

    int N = in_sizes[0] / 8;
    int E = in_sizes[1] / 2;
    int M = E + N;

    // ---- workspace layout, peak ≈ 41.1MB (< known-good 47.2MB) ----
    // A [0,68N): h1(32N)|asr1(2N)|adt1(2N)|out1(32N); hfin overlays A[0,64N) post-node2
    // B [68N,132N): h2(64N); g overlays B post-conv2
    // C: asr2(2N)|adt2(2N)|deg(N)|curs(N)|rowp(N+1)|adj(M)|eid(M)
    float* h1   = (float*)d_ws;
    float* asr1 = h1   + (size_t)N * 32;
    float* adt1 = asr1 + (size_t)N * 2;
    float* out1 = adt1 + (size_t)N * 2;
    float* h2   = out1 + (size_t)N * 32;
    float* asr2 = h2   + (size_t)N * 64;
    float* adt2 = asr2 + (size_t)N * 2;
    int*   deg  = (int*)(adt2 + (size_t)N * 2);
    int*   curs = deg  + N;
    int*   rowp = curs + N;
    int*   adj  = rowp + (N + 1);
    int*   eid  = adj  + M;
    float* hfin = h1;   // A[0,64N): h1/asr1/adt1/out1-prefix all dead by conv2
    float* g    = h2;   // h2 dead after conv2

    int B = 256;
    k_node1<<<(N + B - 1) / B, B, 0, stream>>>(x, W1, as1, ad1, h1, asr1, adt1, N);
    k_deg_init<<<(N + B - 1) / B, B, 0, stream>>>(deg, rowp, N, E);
    k_deg_count<<<(E + B - 1) / B, B, 0, stream>>>(ei, deg, E);
    k_scan<<<1, 1024, 0, stream>>>(deg, rowp, curs, N);
    k_scatter<<<(M + B - 1) / B, B, 0, stream>>>(ei, curs, adj, eid, E, N);
    {
        long long thr = (long long)((N + 1) / 2) * 64;
        k_conv1<<<(int)((thr + B - 1) / B), B, 0, stream>>>(rowp, adj, asr1, adt1, h1, b1, out1, N);
    }
    {
        long long thr = (long long)N * 64;
        k_node2<<<(int)((thr + B - 1) / B), B, 0, stream>>>(out1, W2, as2, ad2, h2, asr2, adt2, N);
    }
    {
        long long thr = (long long)N * 64;
        k_conv2<<<(int)((thr + B - 1) / B), B, 0, stream>>>(rowp, adj, asr2, adt2, h2, b2, hfin, N);
    }
    {
        long long thr = (long long)N * 64;
        k_fc1node<<<(int)((thr + B - 1) / B), B, 0, stream>>>(hfin, fw1, fb1, g, N);
    }
    {
        long long thr = (long long)N * 64;
        k_head3<<<(int)((thr + B - 1) / B), B, 0, stream>>>(rowp, adj, eid, g, fw2, fb2, out, N);
    }
}

// Round 7
// 655.114 us; speedup vs baseline: 1.1565x; 1.1565x over previous
//
#include <hip/hip_runtime.h>
#include <math.h>

#define NEG_SLOPE 0.2f

// ---------------- node transform for conv1: h1 = x@W1, a_src1, a_dst1 ----------------
__global__ void k_node1(const float* __restrict__ x, const float* __restrict__ W1,
                        const float* __restrict__ as1, const float* __restrict__ ad1,
                        float* __restrict__ h1, float* __restrict__ a_src1,
                        float* __restrict__ a_dst1, int N) {
    int n = blockIdx.x * blockDim.x + threadIdx.x;
    if (n >= N) return;
    float xv[8];
#pragma unroll
    for (int k = 0; k < 8; k++) xv[k] = x[n * 8 + k];
    float h[32];
#pragma unroll
    for (int j = 0; j < 32; j++) {
        float acc = 0.f;
#pragma unroll
        for (int k = 0; k < 8; k++) acc += xv[k] * W1[k * 32 + j];
        h[j] = acc;
        h1[n * 32 + j] = acc;
    }
#pragma unroll
    for (int hh = 0; hh < 2; hh++) {
        float s = 0.f, d = 0.f;
#pragma unroll
        for (int c = 0; c < 16; c++) {
            s += h[hh * 16 + c] * as1[hh * 16 + c];
            d += h[hh * 16 + c] * ad1[hh * 16 + c];
        }
        a_src1[n * 2 + hh] = s;
        a_dst1[n * 2 + hh] = d;
    }
}

// ---------------- CSR build ----------------
__global__ void k_deg_init(int* __restrict__ deg, int* __restrict__ rowptr, int N, int E) {
    int n = blockIdx.x * blockDim.x + threadIdx.x;
    if (n < N) deg[n] = 1;  // self-loop
    if (n == 0) rowptr[N] = E + N;
}

__global__ void k_deg_count(const int* __restrict__ ei, int* __restrict__ deg, int E) {
    int e = blockIdx.x * blockDim.x + threadIdx.x;
    if (e < E) atomicAdd(&deg[ei[E + e]], 1);  // dst
}

// 1024-thread single-block hierarchical scan
__global__ void k_scan(const int* __restrict__ deg, int* __restrict__ rowptr,
                       int* __restrict__ cursor, int N) {
    __shared__ int wsum[16];
    __shared__ int wpre[16];
    int tid = threadIdx.x;
    int lane = tid & 63, wid = tid >> 6;
    int chunk = (N + 1023) >> 10;
    int beg = tid * chunk;
    int end = beg + chunk; if (end > N) end = N;
    int s = 0;
    for (int i = beg; i < end; i++) s += deg[i];
    int incl = s;
#pragma unroll
    for (int off = 1; off < 64; off <<= 1) {
        int v = __shfl_up(incl, off);
        if (lane >= off) incl += v;
    }
    if (lane == 63) wsum[wid] = incl;
    __syncthreads();
    if (tid == 0) {
        int r = 0;
        for (int i = 0; i < 16; i++) { wpre[i] = r; r += wsum[i]; }
    }
    __syncthreads();
    int run = wpre[wid] + incl - s;
    for (int i = beg; i < end; i++) {
        rowptr[i] = run;
        cursor[i] = run;
        run += deg[i];
    }
}

// scatter with original-edge-id tracking (eid = -1 for appended self-loops)
__global__ void k_scatter(const int* __restrict__ ei, int* __restrict__ cursor,
                          int* __restrict__ adj, int* __restrict__ eid, int E, int N) {
    int i = blockIdx.x * blockDim.x + threadIdx.x;
    if (i >= E + N) return;
    int s, d, id;
    if (i < E) { s = ei[i]; d = ei[E + i]; id = i; }
    else { s = i - E; d = i - E; id = -1; }
    int pos = atomicAdd(&cursor[d], 1);
    adj[pos] = s;
    eid[pos] = id;
}

// ---------------- conv1: 2 nodes/wave, two-pass exact softmax (R6 verbatim) ----------------
__global__ void k_conv1(const int* __restrict__ rowptr, const int* __restrict__ adj,
                        const float* __restrict__ a_src, const float* __restrict__ a_dst,
                        const float* __restrict__ h1, const float* __restrict__ b1,
                        float* __restrict__ out1, int N) {
    int lane = threadIdx.x & 63;
    int wave = (blockIdx.x * blockDim.x + threadIdx.x) >> 6;
    int sub = lane & 31;           // channel 0..31
    int slot = lane >> 5;
    int hh = sub >> 4;             // head of this lane's channel
    int n = wave * 2 + slot;
    if (n >= N) return;
    int beg = rowptr[n], end = rowptr[n + 1];
    float ad = a_dst[n * 2 + hh];
    float m = -1e30f;
    for (int i = beg + (sub & 15); i < end; i += 16) {
        int s = adj[i];
        float t = a_src[s * 2 + hh] + ad;
        t = t > 0.f ? t : NEG_SLOPE * t;
        m = fmaxf(m, t);
    }
#pragma unroll
    for (int off = 8; off >= 1; off >>= 1) m = fmaxf(m, __shfl_xor(m, off));
    float denom = 0.f, acc = 0.f;
    for (int j0 = beg; j0 < end; j0 += 32) {
        int idx = j0 + sub;
        int av = (idx < end) ? adj[idx] : 0;
        int cnt = end - j0; if (cnt > 32) cnt = 32;
#pragma unroll 8
        for (int jj = 0; jj < cnt; jj++) {
            int s = __shfl(av, jj, 32);
            float t = a_src[s * 2 + hh] + ad;
            t = t > 0.f ? t : NEG_SLOPE * t;
            float wgt = __expf(t - m);
            acc += wgt * h1[s * 32 + sub];
            denom += wgt;
        }
    }
    out1[n * 32 + sub] = fmaxf(acc / denom + b1[sub], 0.f);
}

// ---------------- node transform for conv2 ----------------
__global__ void k_node2(const float* __restrict__ out1, const float* __restrict__ W2,
                        const float* __restrict__ as2, const float* __restrict__ ad2,
                        float* __restrict__ h2, float* __restrict__ a_src2,
                        float* __restrict__ a_dst2, int N) {
    int lane = threadIdx.x & 63;
    int n = (blockIdx.x * blockDim.x + threadIdx.x) >> 6;
    if (n >= N) return;
    float acc = 0.f;
#pragma unroll
    for (int k = 0; k < 32; k++) acc += out1[n * 32 + k] * W2[k * 64 + lane];
    h2[n * 64 + lane] = acc;
    float s = acc * as2[lane];
    float d = acc * ad2[lane];
#pragma unroll
    for (int off = 16; off >= 1; off >>= 1) {
        s += __shfl_xor(s, off);
        d += __shfl_xor(d, off);
    }
    if ((lane & 31) == 0) {
        a_src2[n * 2 + (lane >> 5)] = s;
        a_dst2[n * 2 + (lane >> 5)] = d;
    }
}

// ---------------- conv2: 1 node/wave, two-pass exact softmax (R6 verbatim) ----------------
__global__ void k_conv2(const int* __restrict__ rowptr, const int* __restrict__ adj,
                        const float* __restrict__ a_src, const float* __restrict__ a_dst,
                        const float* __restrict__ h2, const float* __restrict__ b2,
                        float* __restrict__ hfin, int N) {
    int lane = threadIdx.x & 63;
    int n = (blockIdx.x * blockDim.x + threadIdx.x) >> 6;
    if (n >= N) return;
    int hh = lane >> 5;
    int beg = rowptr[n], end = rowptr[n + 1];
    float ad = a_dst[n * 2 + hh];
    float m = -1e30f;
    for (int i = beg + (lane & 31); i < end; i += 32) {
        int s = adj[i];
        float t = a_src[s * 2 + hh] + ad;
        t = t > 0.f ? t : NEG_SLOPE * t;
        m = fmaxf(m, t);
    }
#pragma unroll
    for (int off = 16; off >= 1; off >>= 1) m = fmaxf(m, __shfl_xor(m, off));
    float denom = 0.f, acc = 0.f;
    for (int j0 = beg; j0 < end; j0 += 64) {
        int idx = j0 + lane;
        int av = (idx < end) ? adj[idx] : 0;
        int cnt = end - j0; if (cnt > 64) cnt = 64;
#pragma unroll 8
        for (int jj = 0; jj < cnt; jj++) {
            int s = __shfl(av, jj);
            float t = a_src[s * 2 + hh] + ad;
            t = t > 0.f ? t : NEG_SLOPE * t;
            float wgt = __expf(t - m);
            acc += wgt * h2[s * 64 + lane];
            denom += wgt;
        }
    }
    hfin[n * 64 + lane] = fmaxf(acc / denom + b2[lane], 0.f);
}

// ---------------- per-node fc1: g = hfin @ fc1_w + 0.5*b1 ----------------
__global__ void k_fc1node(const float* __restrict__ hfin, const float* __restrict__ w1,
                          const float* __restrict__ b1, float* __restrict__ g, int N) {
    int lane = threadIdx.x & 63;
    int n = (blockIdx.x * blockDim.x + threadIdx.x) >> 6;
    if (n >= N) return;
    float hv = hfin[n * 64 + lane];
    float acc = 0.5f * b1[lane];
#pragma unroll
    for (int k = 0; k < 64; k++) acc += __shfl(hv, k) * w1[k * 64 + lane];
    g[n * 64 + lane] = acc;
}

// ---------------- edge head v4: thread-per-CSR-slot, dst-locality, per-thread dot ----------------
// dst node derived by binary search in rowp (L1/L2-hot, top levels wave-uniform).
// g[dst] shared by ~deg consecutive threads (L1 broadcast); g[src] is the only
// random gather. No cross-lane reduce -> full thread parallelism.
__global__ void k_head4(const int* __restrict__ rowp, const int* __restrict__ adj,
                        const int* __restrict__ eid, const float* __restrict__ g,
                        const float* __restrict__ w2, const float* __restrict__ b2,
                        float* __restrict__ out, int M, int N) {
    int t = blockIdx.x * blockDim.x + threadIdx.x;
    if (t >= M) return;
    int id = eid[t];
    if (id < 0) return;            // appended self-loop: not an output edge
    // binary search: n such that rowp[n] <= t < rowp[n+1]
    int lo = 0, hi = N;
    while (hi - lo > 1) {
        int mid = (lo + hi) >> 1;
        if (rowp[mid] <= t) lo = mid; else hi = mid;
    }
    int n = lo;
    int r = adj[t];
    const float4* gr = (const float4*)(g + (size_t)r * 64);
    const float4* gc = (const float4*)(g + (size_t)n * 64);
    float o = b2[0];
#pragma unroll
    for (int q = 0; q < 16; q++) {
        float4 a = gr[q], b = gc[q];
        o += fmaxf(a.x + b.x, 0.f) * w2[4 * q + 0];
        o += fmaxf(a.y + b.y, 0.f) * w2[4 * q + 1];
        o += fmaxf(a.z + b.z, 0.f) * w2[4 * q + 2];
        o += fmaxf(a.w + b.w, 0.f) * w2[4 * q + 3];
    }
    out[id] = o;
}

extern "C" void kernel_launch(void* const* d_in, const int* in_sizes, int n_in,
                              void* d_out, int out_size, void* d_ws, size_t ws_size,
                              hipStream_t stream) {
    const float* x   = (const float*)d_in[0];
    const int*   ei  = (const int*)d_in[1];
    const float* W1  = (const float*)d_in[2];
    const float* as1 = (const float*)d_in[3];
    const float* ad1 = (const float*)d_in[4];
    const float* b1  = (const float*)d_in[5];
    const float* W2  = (const float*)d_in[6];
    const float* as2 = (const float*)d_in[7];
    const float* ad2 = (const float*)d_in[8];
    const float* b2  = (const float*)d_in[9];
    const float* fw1 = (const float*)d_in[10];
    const float* fb1 = (const float*)d_in[11];
    const float* fw2 = (const float*)d_in[12];
    const float* fb2 = (const float*)d_in[13];
    float* out = (float*)d_out;

    int N = in_sizes[0] / 8;
    int E = in_sizes[1] / 2;
    int M = E + N;

    // ---- workspace layout (R6 verbatim, peak ≈ 41.1MB) ----
    float* h1   = (float*)d_ws;
    float* asr1 = h1   + (size_t)N * 32;
    float* adt1 = asr1 + (size_t)N * 2;
    float* out1 = adt1 + (size_t)N * 2;
    float* h2   = out1 + (size_t)N * 32;
    float* asr2 = h2   + (size_t)N * 64;
    float* adt2 = asr2 + (size_t)N * 2;
    int*   deg  = (int*)(adt2 + (size_t)N * 2);
    int*   curs = deg  + N;
    int*   rowp = curs + N;
    int*   adj  = rowp + (N + 1);
    int*   eid  = adj  + M;
    float* hfin = h1;   // layer-1 region dead by conv2
    float* g    = h2;   // h2 dead after conv2

    int B = 256;
    k_node1<<<(N + B - 1) / B, B, 0, stream>>>(x, W1, as1, ad1, h1, asr1, adt1, N);
    k_deg_init<<<(N + B - 1) / B, B, 0, stream>>>(deg, rowp, N, E);
    k_deg_count<<<(E + B - 1) / B, B, 0, stream>>>(ei, deg, E);
    k_scan<<<1, 1024, 0, stream>>>(deg, rowp, curs, N);
    k_scatter<<<(M + B - 1) / B, B, 0, stream>>>(ei, curs, adj, eid, E, N);
    {
        long long thr = (long long)((N + 1) / 2) * 64;
        k_conv1<<<(int)((thr + B - 1) / B), B, 0, stream>>>(rowp, adj, asr1, adt1, h1, b1, out1, N);
    }
    {
        long long thr = (long long)N * 64;
        k_node2<<<(int)((thr + B - 1) / B), B, 0, stream>>>(out1, W2, as2, ad2, h2, asr2, adt2, N);
    }
    {
        long long thr = (long long)N * 64;
        k_conv2<<<(int)((thr + B - 1) / B), B, 0, stream>>>(rowp, adj, asr2, adt2, h2, b2, hfin, N);
    }
    {
        long long thr = (long long)N * 64;
        k_fc1node<<<(int)((thr + B - 1) / B), B, 0, stream>>>(hfin, fw1, fb1, g, N);
    }
    k_head4<<<(M + B - 1) / B, B, 0, stream>>>(rowp, adj, eid, g, fw2, fb2, out, M, N);
}